// Round 15
// baseline (166.810 us; speedup 1.0000x reference)
//
#include <hip/hip_runtime.h>
#include <math.h>

// ---------------------------------------------------------------------------
// GATv2 encoder. r14 = 162.7us. This round: aggregate v6 only -
// (1) 8-deep gather pipeline (vs 4): more loads in flight per wave;
// (2) 128-thread blocks (2 waves): block exits at max-of-2 Poisson degrees
//     (~18) not max-of-4 (~25) -> less wave-residency waste.
// All other kernels frozen at r14 baseline.
// ---------------------------------------------------------------------------

#define D 128
#define H 8
#define C 16
#define NBIN 256

typedef __attribute__((ext_vector_type(8))) short bf16x8v;
typedef __attribute__((ext_vector_type(4))) float f32x4v;

static __device__ __forceinline__ float bf2f(unsigned int u16) {
    union { unsigned int i; float f; } x; x.i = u16 << 16; return x.f;
}
static __device__ __forceinline__ unsigned short f2bf(float f) {
    union { float f; unsigned int i; } x; x.f = f;
    unsigned int r = x.i + 0x7fffu + ((x.i >> 16) & 1u);   // RNE
    return (unsigned short)(r >> 16);
}
static __device__ __forceinline__ float gelu_f(float v) {
    return 0.5f * v * (1.0f + erff(v * 0.70710678118654752f));
}
static __device__ __forceinline__ float exp2_hw(float x) {   // v_exp_f32 = 2^x
    float r;
    asm("v_exp_f32 %0, %1" : "=v"(r) : "v"(x));
    return r;
}
#define DPP_ADD(v, ctrl) \
    (v) += __builtin_bit_cast(float, __builtin_amdgcn_update_dpp( \
        0, __builtin_bit_cast(int, (v)), (ctrl), 0xf, 0xf, true))

// ----------------------- GEMM body (no LDS) --------------------------------
template<int IN_BF, int OUT_BF, int GELU>
static __device__ __forceinline__ void gemm_body(
    int bid, const void* __restrict__ Xv, const unsigned short* __restrict__ Wt,
    const float* __restrict__ bias, void* __restrict__ Outv, int nrows)
{
    const int t  = threadIdx.x;
    const int l  = t & 63;
    const int wv = t >> 6;
    const int g  = l >> 4;
    const int r  = l & 15;
    const int m0 = bid * 64;
    const int row = m0 + wv * 16 + r;
    const bool rv = row < nrows;
    const uint4* Wt4 = reinterpret_cast<const uint4*>(Wt);

    bf16x8v afrag[4];
#pragma unroll
    for (int kk = 0; kk < 4; ++kk) {
        int kg = kk * 4 + g;
        float v[8];
        if (IN_BF) {
            uint4 q = make_uint4(0, 0, 0, 0);
            if (rv) q = reinterpret_cast<const uint4*>(Xv)[(size_t)row * 16 + kg];
            if (GELU) {
                unsigned int qq[4] = {q.x, q.y, q.z, q.w};
#pragma unroll
                for (int j = 0; j < 4; ++j) {
                    v[2 * j]     = gelu_f(bf2f(qq[j] & 0xffffu));
                    v[2 * j + 1] = gelu_f(bf2f(qq[j] >> 16));
                }
                short pk[8];
#pragma unroll
                for (int j = 0; j < 8; ++j) pk[j] = (short)f2bf(v[j]);
                afrag[kk] = *reinterpret_cast<bf16x8v*>(pk);
            } else {
                afrag[kk] = __builtin_bit_cast(bf16x8v, q);
            }
        } else {
            float4 a = make_float4(0.f, 0.f, 0.f, 0.f), b = a;
            if (rv) {
                a = reinterpret_cast<const float4*>(Xv)[(size_t)row * 32 + kg * 2];
                b = reinterpret_cast<const float4*>(Xv)[(size_t)row * 32 + kg * 2 + 1];
            }
            v[0] = a.x; v[1] = a.y; v[2] = a.z; v[3] = a.w;
            v[4] = b.x; v[5] = b.y; v[6] = b.z; v[7] = b.w;
            if (GELU) {
#pragma unroll
                for (int j = 0; j < 8; ++j) v[j] = gelu_f(v[j]);
            }
            short pk[8];
#pragma unroll
            for (int j = 0; j < 8; ++j) pk[j] = (short)f2bf(v[j]);
            afrag[kk] = *reinterpret_cast<bf16x8v*>(pk);
        }
    }

    f32x4v acc[8];
#pragma unroll
    for (int ct = 0; ct < 8; ++ct) acc[ct] = (f32x4v){0.f, 0.f, 0.f, 0.f};

    bf16x8v bA[8], bB[8];
#pragma unroll
    for (int ct = 0; ct < 8; ++ct)
        bA[ct] = __builtin_bit_cast(bf16x8v, Wt4[(ct * 16 + r) * 16 + g]);

#pragma unroll
    for (int kk = 0; kk < 4; ++kk) {
        if (kk < 3) {
            int kgn = (kk + 1) * 4 + g;
#pragma unroll
            for (int ct = 0; ct < 8; ++ct) {
                bf16x8v v = __builtin_bit_cast(bf16x8v, Wt4[(ct * 16 + r) * 16 + kgn]);
                if (kk & 1) bA[ct] = v; else bB[ct] = v;
            }
        }
#pragma unroll
        for (int ct = 0; ct < 8; ++ct) {
            bf16x8v b = (kk & 1) ? bB[ct] : bA[ct];
            acc[ct] = __builtin_amdgcn_mfma_f32_16x16x32_bf16(afrag[kk], b, acc[ct], 0, 0, 0);
        }
    }

#pragma unroll
    for (int ct = 0; ct < 8; ++ct) {
        int col = ct * 16 + r;
        float bj = bias ? bias[col] : 0.f;
#pragma unroll
        for (int i = 0; i < 4; ++i) {
            int rr = m0 + wv * 16 + g * 4 + i;
            if (rr < nrows) {
                float val = acc[ct][i] + bj;
                if (OUT_BF)
                    reinterpret_cast<unsigned short*>(Outv)[(size_t)rr * 128 + col] = f2bf(val);
                else
                    reinterpret_cast<float*>(Outv)[(size_t)rr * 128 + col] = val;
            }
        }
    }
}

// --------------- head GEMM with fused LayerNorm epilogue -------------------
__global__ __launch_bounds__(256) void gemm_head_ln(
    const void* __restrict__ Xv, const unsigned short* __restrict__ Wt,
    const float* __restrict__ outb, const float* __restrict__ lng,
    const float* __restrict__ lnb, float* __restrict__ Out, int nrows)
{
    const int t  = threadIdx.x;
    const int l  = t & 63;
    const int wv = t >> 6;
    const int g  = l >> 4;
    const int r  = l & 15;
    const int m0 = blockIdx.x * 64;
    const int row = m0 + wv * 16 + r;
    const bool rv = row < nrows;
    const uint4* Wt4 = reinterpret_cast<const uint4*>(Wt);

    bf16x8v afrag[4];
#pragma unroll
    for (int kk = 0; kk < 4; ++kk) {
        int kg = kk * 4 + g;
        uint4 q = make_uint4(0, 0, 0, 0);
        if (rv) q = reinterpret_cast<const uint4*>(Xv)[(size_t)row * 16 + kg];
        afrag[kk] = __builtin_bit_cast(bf16x8v, q);
    }

    f32x4v acc[8];
#pragma unroll
    for (int ct = 0; ct < 8; ++ct) acc[ct] = (f32x4v){0.f, 0.f, 0.f, 0.f};

#pragma unroll
    for (int kk = 0; kk < 4; ++kk) {
        int kg = kk * 4 + g;
#pragma unroll
        for (int ct = 0; ct < 8; ++ct) {
            bf16x8v b = __builtin_bit_cast(bf16x8v, Wt4[(ct * 16 + r) * 16 + kg]);
            acc[ct] = __builtin_amdgcn_mfma_f32_16x16x32_bf16(afrag[kk], b, acc[ct], 0, 0, 0);
        }
    }

    float gmm[8], bbb[8];
#pragma unroll
    for (int ct = 0; ct < 8; ++ct) {
        gmm[ct] = lng[ct * 16 + r];
        bbb[ct] = lnb[ct * 16 + r];
    }

#pragma unroll
    for (int i = 0; i < 4; ++i) {
        int rr = m0 + wv * 16 + g * 4 + i;
        if (rr >= nrows) continue;   // uniform within the 16-lane row group
        float v[8];
        float s = 0.f;
#pragma unroll
        for (int ct = 0; ct < 8; ++ct) {
            v[ct] = acc[ct][i] + outb[ct * 16 + r];
            s += v[ct];
        }
        DPP_ADD(s, 0xB1); DPP_ADD(s, 0x4E); DPP_ADD(s, 0x141); DPP_ADD(s, 0x140);
        float mu = s * (1.f / 128.f);
        float q = 0.f;
#pragma unroll
        for (int ct = 0; ct < 8; ++ct) {
            float dd = v[ct] - mu;
            q += dd * dd;
        }
        DPP_ADD(q, 0xB1); DPP_ADD(q, 0x4E); DPP_ADD(q, 0x141); DPP_ADD(q, 0x140);
        float inv = rsqrtf(q * (1.f / 128.f) + 1e-12f);
#pragma unroll
        for (int ct = 0; ct < 8; ++ct)
            Out[(size_t)rr * 128 + ct * 16 + r] = (v[ct] - mu) * inv * gmm[ct] + bbb[ct];
    }
}

// ---------------- K1: W transpose (24 blocks) || edge histogram ------------
__global__ __launch_bounds__(256) void prep_kernel(
    const float* __restrict__ W, const float* __restrict__ outW,
    unsigned short* __restrict__ wbf,
    const int* __restrict__ dst, int* __restrict__ bh,
    int E, int chunk, int nblk)
{
    __shared__ char smem[128 * 17 * 2];
    int t = threadIdx.x;
    if (blockIdx.x < 24) {
        unsigned short (*tile)[17] = reinterpret_cast<unsigned short (*)[17]>(smem);
        int blk = blockIdx.x;
        int mat = blk >> 3, s = blk & 7;
        const float* src = (mat < 2) ? (W + (size_t)mat * D * D) : outW;
        unsigned short* dstp = wbf + (size_t)mat * D * D;
        int n0 = s * 16;
#pragma unroll
        for (int it = 0; it < 8; ++it) {
            int idx = it * 256 + t;
            int k = idx >> 4, n = idx & 15;
            tile[k][n] = f2bf(src[k * D + n0 + n]);
        }
        __syncthreads();
#pragma unroll
        for (int it = 0; it < 8; ++it) {
            int idx = it * 256 + t;
            int n = idx >> 7, k = idx & 127;
            dstp[(size_t)(n0 + n) * D + k] = tile[k][n];
        }
    } else {
        int* h = reinterpret_cast<int*>(smem);
        int b = blockIdx.x - 24;
        h[t] = 0;
        __syncthreads();
        int lo = b * chunk, hi = min(E, lo + chunk);
        for (int i = lo + t; i < hi; i += 256) atomicAdd(&h[dst[i] >> 8], 1);
        __syncthreads();
        bh[t * nblk + b] = h[t];
    }
}

// ---------------- K2: bin_scan (NBIN blocks) || gemm layer-0 ---------------
__global__ __launch_bounds__(256) void scan_gemm0(
    int* __restrict__ bh, int* __restrict__ tot, int nblk,
    const float* __restrict__ x, const unsigned short* __restrict__ wbf,
    void* __restrict__ hbuf, int nrows)
{
    __shared__ int sh[256];
    int t = threadIdx.x;
    if (blockIdx.x < NBIN) {
        int bin = blockIdx.x;
        int v = (t < nblk) ? bh[bin * nblk + t] : 0;
        sh[t] = v;
        __syncthreads();
#pragma unroll
        for (int off = 1; off < 256; off <<= 1) {
            int xq = (t >= off) ? sh[t - off] : 0;
            __syncthreads();
            sh[t] += xq;
            __syncthreads();
        }
        if (t < nblk) bh[bin * nblk + t] = sh[t] - v;
        if (t == 255) tot[bin] = sh[255];
    } else {
        gemm_body<0, 1, 0>(blockIdx.x - NBIN, x, wbf, nullptr, hbuf, nrows);
    }
}

// ---------------- standalone gemm layer-1 (bf16 in, gelu) ------------------
__global__ __launch_bounds__(256) void gemm_l1(
    const void* __restrict__ Xv, const unsigned short* __restrict__ Wt,
    void* __restrict__ Outv, int nrows)
{
    gemm_body<1, 1, 1>(blockIdx.x, Xv, Wt, nullptr, Outv, nrows);
}

// ------------------- CSR build (scatter + fused fill) ----------------------
__global__ __launch_bounds__(256) void scatter_bucket2(
    const int* __restrict__ dst, const int* __restrict__ src,
    const int* __restrict__ bh, const int* __restrict__ tot,
    int2* __restrict__ bout, int E, int chunk, int nblk)
{
    __shared__ int sh[NBIN];
    __shared__ int cur[NBIN];
    int t = threadIdx.x, b = blockIdx.x;
    int tv = tot[t];
    sh[t] = tv;
    __syncthreads();
#pragma unroll
    for (int off = 1; off < 256; off <<= 1) {
        int x = (t >= off) ? sh[t - off] : 0;
        __syncthreads();
        sh[t] += x;
        __syncthreads();
    }
    cur[t] = (sh[t] - tv) + bh[t * nblk + b];
    __syncthreads();
    int lo = b * chunk, hi = min(E, lo + chunk);
    for (int i = lo + t; i < hi; i += 256) {
        int d = dst[i];
        int p = atomicAdd(&cur[d >> 8], 1);
        bout[p] = make_int2(src[i], d);
    }
}

__global__ __launch_bounds__(256) void fill_fused(
    const int2* __restrict__ bout, const int* __restrict__ tot,
    int* __restrict__ rowptr, int* __restrict__ slist, int N, int E)
{
    __shared__ int sh[NBIN];
    __shared__ int cnt[NBIN];
    __shared__ int cur[NBIN];
    int b = blockIdx.x, t = threadIdx.x;

    int tv = tot[t];
    sh[t] = tv;
    __syncthreads();
#pragma unroll
    for (int off = 1; off < 256; off <<= 1) {
        int x = (t >= off) ? sh[t - off] : 0;
        __syncthreads();
        sh[t] += x;
        __syncthreads();
    }
    int hi = sh[b];
    int lo = hi - tot[b];

    cnt[t] = 0;
    __syncthreads();
    for (int i = lo + t; i < hi; i += 256) atomicAdd(&cnt[bout[i].y & 255], 1);
    __syncthreads();

    int cv = cnt[t];
    sh[t] = cv;
    __syncthreads();
#pragma unroll
    for (int off = 1; off < 256; off <<= 1) {
        int x = (t >= off) ? sh[t - off] : 0;
        __syncthreads();
        sh[t] += x;
        __syncthreads();
    }
    int start = lo + sh[t] - cv;
    int d0 = b * 256 + t;
    if (d0 < N) rowptr[d0] = start;
    if (b == (int)gridDim.x - 1 && t == 255) rowptr[N] = E;
    cur[t] = start;
    __syncthreads();

    for (int i = lo + t; i < hi; i += 256) {
        int2 e = bout[i];
        int p = atomicAdd(&cur[e.y & 255], 1);
        slist[p] = e.x;
    }
}

// ----------- aggregate v6: 8-deep pipeline, 2 waves/block ------------------
// wave per dst node; lane = channels (2*lane,2*lane+1); head = lane>>3.
__global__ __launch_bounds__(128) void aggregate(
    const unsigned int* __restrict__ Hm,
    const int* __restrict__ rowptr, const int* __restrict__ slist,
    const float* __restrict__ att, const float* __restrict__ bias,
    unsigned int* __restrict__ Outv, int n)
{
    int wid  = threadIdx.x >> 6;
    int lane = threadIdx.x & 63;
    int d = blockIdx.x * 2 + wid;
    if (d >= n) return;

    int beg = __builtin_amdgcn_readfirstlane(rowptr[d]);
    int end = __builtin_amdgcn_readfirstlane(rowptr[d + 1]);

    unsigned int ud = Hm[((unsigned)d << 6) | lane];
    float hdx = bf2f(ud & 0xffffu), hdy = bf2f(ud >> 16);
    float2 aw = reinterpret_cast<const float2*>(att)[lane];
    aw.x *= 1.44269504088896f;    // fold log2(e): exp(p) = 2^(p*log2e)
    aw.y *= 1.44269504088896f;

    float ssum = 0.f, accx = 0.f, accy = 0.f;

#define EDGE_DO(U) { \
        unsigned u = (U); \
        float hx = bf2f(u & 0xffffu), hy = bf2f(u >> 16); \
        float a = hx + hdx; a = fmaxf(a, 0.2f * a); \
        float b = hy + hdy; b = fmaxf(b, 0.2f * b); \
        float p = a * aw.x + b * aw.y; \
        DPP_ADD(p, 0xB1); DPP_ADD(p, 0x4E); DPP_ADD(p, 0x141); \
        float e = exp2_hw(p); \
        ssum += e; \
        accx = fmaf(e, hx, accx); \
        accy = fmaf(e, hy, accy); }

    int cnt = end - beg;
    int n8 = cnt >> 3;
    int ii = beg;
    unsigned cu[8];
    if (n8) {
#pragma unroll
        for (int k = 0; k < 8; ++k)
            cu[k] = Hm[((unsigned)slist[ii + k] << 6) | lane];
        for (int q = 1; q < n8; ++q) {
            int j = ii + 8;
            unsigned nu[8];
#pragma unroll
            for (int k = 0; k < 8; ++k)
                nu[k] = Hm[((unsigned)slist[j + k] << 6) | lane];
#pragma unroll
            for (int k = 0; k < 8; ++k) EDGE_DO(cu[k])
#pragma unroll
            for (int k = 0; k < 8; ++k) cu[k] = nu[k];
            ii = j;
        }
#pragma unroll
        for (int k = 0; k < 8; ++k) EDGE_DO(cu[k])
        ii += 8;
    }
    for (; ii < end; ++ii) {
        unsigned u0 = Hm[((unsigned)slist[ii] << 6) | lane];
        EDGE_DO(u0)
    }
#undef EDGE_DO

    float inv = 1.f / (ssum + 1e-16f);
    float2 bv = reinterpret_cast<const float2*>(bias)[lane];
    float ox = accx * inv + bv.x;
    float oy = accy * inv + bv.y;
    Outv[((unsigned)d << 6) | lane] =
        (unsigned int)f2bf(ox) | ((unsigned int)f2bf(oy) << 16);
}

// ---------------------------------------------------------------------------
extern "C" void kernel_launch(void* const* d_in, const int* in_sizes, int n_in,
                              void* d_out, int out_size, void* d_ws, size_t ws_size,
                              hipStream_t stream)
{
    const float* x    = (const float*)d_in[0];
    const int*   edge = (const int*)d_in[1];     // int32 (harness converts int64)
    const float* W    = (const float*)d_in[2];
    const float* att  = (const float*)d_in[3];
    const float* bias = (const float*)d_in[4];
    const float* outW = (const float*)d_in[5];
    const float* outb = (const float*)d_in[6];
    const float* lng  = (const float*)d_in[7];
    const float* lnb  = (const float*)d_in[8];

    const int N  = in_sizes[0] / D;
    const int E  = in_sizes[1] / 2;
    const int NT = out_size / D;

    const int* srcp = edge;
    const int* dstp = edge + E;

    auto align256 = [](size_t v) { return (v + 255) & ~(size_t)255; };
    auto cdiv = [](int a, int b) { return (a + b - 1) / b; };

    const int CHUNK = cdiv(E, 256);
    const int NBLK  = cdiv(E, CHUNK);        // <= 256
    const int NBKT  = cdiv(N, 256);
    const int NG    = cdiv(N, 64);           // gemm blocks (N rows)

    char* wp = (char*)d_ws;
    size_t off = 0;
    void* hbuf   = (void*)(wp + off); off += align256((size_t)N * D * 2);
    void* xbuf   = (void*)(wp + off); off += align256((size_t)N * D * 2);
    unsigned short* wbf = (unsigned short*)(wp + off); off += align256((size_t)3 * D * D * 2);
    int*  rowptr = (int*)(wp + off);  off += align256((size_t)(N + 1) * 4);
    int*  slist  = (int*)(wp + off);  off += align256((size_t)E * 4);
    int2* bout   = (int2*)(wp + off); off += align256((size_t)E * 8);
    int*  bh     = (int*)(wp + off);  off += align256((size_t)NBIN * NBLK * 4);
    int*  tot    = (int*)(wp + off);  off += align256((size_t)NBIN * 4);
    (void)n_in; (void)ws_size;

    // K1: W transpose (24 blocks) || edge histogram (NBLK blocks)
    prep_kernel<<<24 + NBLK, 256, 0, stream>>>(W, outW, wbf, dstp, bh, E, CHUNK, NBLK);
    // K2: bin_scan (NBIN) || gemm layer-0 (NG)
    scan_gemm0<<<NBIN + NG, 256, 0, stream>>>(bh, tot, NBLK, x, wbf, hbuf, N);
    // K3/K4: scatter + fill
    scatter_bucket2<<<NBLK, 256, 0, stream>>>(dstp, srcp, bh, tot, bout, E, CHUNK, NBLK);
    fill_fused<<<NBKT, 256, 0, stream>>>(bout, tot, rowptr, slist, N, E);
    // K5: aggregate layer-0
    aggregate<<<cdiv(N, 2), 128, 0, stream>>>((unsigned int*)hbuf, rowptr, slist,
                                              att, bias, (unsigned int*)xbuf, N);
    // K6: gemm layer-1 (gelu fused on load)
    gemm_l1<<<NG, 256, 0, stream>>>(xbuf, wbf + D * D, hbuf, N);
    // K7: aggregate layer-1
    aggregate<<<cdiv(N, 2), 128, 0, stream>>>((unsigned int*)hbuf, rowptr, slist,
                                              att + H * C, bias + D, (unsigned int*)xbuf, N);
    // K8: head gemm + fused LayerNorm -> d_out
    gemm_head_ln<<<cdiv(NT, 64), 256, 0, stream>>>(xbuf, wbf + 2 * D * D, outb,
                                                   lng, lnb, (float*)d_out, NT);
}

// Round 16
// 154.580 us; speedup vs baseline: 1.0791x; 1.0791x over previous
//
#include <hip/hip_runtime.h>
#include <math.h>

// ---------------------------------------------------------------------------
// GATv2 encoder. r15: 8-deep/2-wave agg regressed (166.8 vs 162.7) -> revert
// to r14 shape. This round: (a) leaky(v)=0.6v+0.4|v| with |v| as free VOP3
// src modifier + 0.6/0.4/log2e folded into two pre-scaled att vectors ->
// logit = 4 FMAs (was 6 ops); (b) K3 = scatter || gemm0 (was gemm0 || tiny
// bin_scan) for better launch packing.
// ---------------------------------------------------------------------------

#define D 128
#define H 8
#define C 16
#define NBIN 256

typedef __attribute__((ext_vector_type(8))) short bf16x8v;
typedef __attribute__((ext_vector_type(4))) float f32x4v;

static __device__ __forceinline__ float bf2f(unsigned int u16) {
    union { unsigned int i; float f; } x; x.i = u16 << 16; return x.f;
}
static __device__ __forceinline__ unsigned short f2bf(float f) {
    union { float f; unsigned int i; } x; x.f = f;
    unsigned int r = x.i + 0x7fffu + ((x.i >> 16) & 1u);   // RNE
    return (unsigned short)(r >> 16);
}
static __device__ __forceinline__ float gelu_f(float v) {
    return 0.5f * v * (1.0f + erff(v * 0.70710678118654752f));
}
static __device__ __forceinline__ float exp2_hw(float x) {   // v_exp_f32 = 2^x
    float r;
    asm("v_exp_f32 %0, %1" : "=v"(r) : "v"(x));
    return r;
}
#define DPP_ADD(v, ctrl) \
    (v) += __builtin_bit_cast(float, __builtin_amdgcn_update_dpp( \
        0, __builtin_bit_cast(int, (v)), (ctrl), 0xf, 0xf, true))

// ----------------------- GEMM body (no LDS) --------------------------------
template<int IN_BF, int OUT_BF, int GELU>
static __device__ __forceinline__ void gemm_body(
    int bid, const void* __restrict__ Xv, const unsigned short* __restrict__ Wt,
    const float* __restrict__ bias, void* __restrict__ Outv, int nrows)
{
    const int t  = threadIdx.x;
    const int l  = t & 63;
    const int wv = t >> 6;
    const int g  = l >> 4;
    const int r  = l & 15;
    const int m0 = bid * 64;
    const int row = m0 + wv * 16 + r;
    const bool rv = row < nrows;
    const uint4* Wt4 = reinterpret_cast<const uint4*>(Wt);

    bf16x8v afrag[4];
#pragma unroll
    for (int kk = 0; kk < 4; ++kk) {
        int kg = kk * 4 + g;
        float v[8];
        if (IN_BF) {
            uint4 q = make_uint4(0, 0, 0, 0);
            if (rv) q = reinterpret_cast<const uint4*>(Xv)[(size_t)row * 16 + kg];
            if (GELU) {
                unsigned int qq[4] = {q.x, q.y, q.z, q.w};
#pragma unroll
                for (int j = 0; j < 4; ++j) {
                    v[2 * j]     = gelu_f(bf2f(qq[j] & 0xffffu));
                    v[2 * j + 1] = gelu_f(bf2f(qq[j] >> 16));
                }
                short pk[8];
#pragma unroll
                for (int j = 0; j < 8; ++j) pk[j] = (short)f2bf(v[j]);
                afrag[kk] = *reinterpret_cast<bf16x8v*>(pk);
            } else {
                afrag[kk] = __builtin_bit_cast(bf16x8v, q);
            }
        } else {
            float4 a = make_float4(0.f, 0.f, 0.f, 0.f), b = a;
            if (rv) {
                a = reinterpret_cast<const float4*>(Xv)[(size_t)row * 32 + kg * 2];
                b = reinterpret_cast<const float4*>(Xv)[(size_t)row * 32 + kg * 2 + 1];
            }
            v[0] = a.x; v[1] = a.y; v[2] = a.z; v[3] = a.w;
            v[4] = b.x; v[5] = b.y; v[6] = b.z; v[7] = b.w;
            if (GELU) {
#pragma unroll
                for (int j = 0; j < 8; ++j) v[j] = gelu_f(v[j]);
            }
            short pk[8];
#pragma unroll
            for (int j = 0; j < 8; ++j) pk[j] = (short)f2bf(v[j]);
            afrag[kk] = *reinterpret_cast<bf16x8v*>(pk);
        }
    }

    f32x4v acc[8];
#pragma unroll
    for (int ct = 0; ct < 8; ++ct) acc[ct] = (f32x4v){0.f, 0.f, 0.f, 0.f};

    bf16x8v bA[8], bB[8];
#pragma unroll
    for (int ct = 0; ct < 8; ++ct)
        bA[ct] = __builtin_bit_cast(bf16x8v, Wt4[(ct * 16 + r) * 16 + g]);

#pragma unroll
    for (int kk = 0; kk < 4; ++kk) {
        if (kk < 3) {
            int kgn = (kk + 1) * 4 + g;
#pragma unroll
            for (int ct = 0; ct < 8; ++ct) {
                bf16x8v v = __builtin_bit_cast(bf16x8v, Wt4[(ct * 16 + r) * 16 + kgn]);
                if (kk & 1) bA[ct] = v; else bB[ct] = v;
            }
        }
#pragma unroll
        for (int ct = 0; ct < 8; ++ct) {
            bf16x8v b = (kk & 1) ? bB[ct] : bA[ct];
            acc[ct] = __builtin_amdgcn_mfma_f32_16x16x32_bf16(afrag[kk], b, acc[ct], 0, 0, 0);
        }
    }

#pragma unroll
    for (int ct = 0; ct < 8; ++ct) {
        int col = ct * 16 + r;
        float bj = bias ? bias[col] : 0.f;
#pragma unroll
        for (int i = 0; i < 4; ++i) {
            int rr = m0 + wv * 16 + g * 4 + i;
            if (rr < nrows) {
                float val = acc[ct][i] + bj;
                if (OUT_BF)
                    reinterpret_cast<unsigned short*>(Outv)[(size_t)rr * 128 + col] = f2bf(val);
                else
                    reinterpret_cast<float*>(Outv)[(size_t)rr * 128 + col] = val;
            }
        }
    }
}

// --------------- head GEMM with fused LayerNorm epilogue -------------------
__global__ __launch_bounds__(256) void gemm_head_ln(
    const void* __restrict__ Xv, const unsigned short* __restrict__ Wt,
    const float* __restrict__ outb, const float* __restrict__ lng,
    const float* __restrict__ lnb, float* __restrict__ Out, int nrows)
{
    const int t  = threadIdx.x;
    const int l  = t & 63;
    const int wv = t >> 6;
    const int g  = l >> 4;
    const int r  = l & 15;
    const int m0 = blockIdx.x * 64;
    const int row = m0 + wv * 16 + r;
    const bool rv = row < nrows;
    const uint4* Wt4 = reinterpret_cast<const uint4*>(Wt);

    bf16x8v afrag[4];
#pragma unroll
    for (int kk = 0; kk < 4; ++kk) {
        int kg = kk * 4 + g;
        uint4 q = make_uint4(0, 0, 0, 0);
        if (rv) q = reinterpret_cast<const uint4*>(Xv)[(size_t)row * 16 + kg];
        afrag[kk] = __builtin_bit_cast(bf16x8v, q);
    }

    f32x4v acc[8];
#pragma unroll
    for (int ct = 0; ct < 8; ++ct) acc[ct] = (f32x4v){0.f, 0.f, 0.f, 0.f};

#pragma unroll
    for (int kk = 0; kk < 4; ++kk) {
        int kg = kk * 4 + g;
#pragma unroll
        for (int ct = 0; ct < 8; ++ct) {
            bf16x8v b = __builtin_bit_cast(bf16x8v, Wt4[(ct * 16 + r) * 16 + kg]);
            acc[ct] = __builtin_amdgcn_mfma_f32_16x16x32_bf16(afrag[kk], b, acc[ct], 0, 0, 0);
        }
    }

    float gmm[8], bbb[8];
#pragma unroll
    for (int ct = 0; ct < 8; ++ct) {
        gmm[ct] = lng[ct * 16 + r];
        bbb[ct] = lnb[ct * 16 + r];
    }

#pragma unroll
    for (int i = 0; i < 4; ++i) {
        int rr = m0 + wv * 16 + g * 4 + i;
        if (rr >= nrows) continue;   // uniform within the 16-lane row group
        float v[8];
        float s = 0.f;
#pragma unroll
        for (int ct = 0; ct < 8; ++ct) {
            v[ct] = acc[ct][i] + outb[ct * 16 + r];
            s += v[ct];
        }
        DPP_ADD(s, 0xB1); DPP_ADD(s, 0x4E); DPP_ADD(s, 0x141); DPP_ADD(s, 0x140);
        float mu = s * (1.f / 128.f);
        float q = 0.f;
#pragma unroll
        for (int ct = 0; ct < 8; ++ct) {
            float dd = v[ct] - mu;
            q += dd * dd;
        }
        DPP_ADD(q, 0xB1); DPP_ADD(q, 0x4E); DPP_ADD(q, 0x141); DPP_ADD(q, 0x140);
        float inv = rsqrtf(q * (1.f / 128.f) + 1e-12f);
#pragma unroll
        for (int ct = 0; ct < 8; ++ct)
            Out[(size_t)rr * 128 + ct * 16 + r] = (v[ct] - mu) * inv * gmm[ct] + bbb[ct];
    }
}

// ---------------- K1: W transpose (24 blocks) || edge histogram ------------
__global__ __launch_bounds__(256) void prep_kernel(
    const float* __restrict__ W, const float* __restrict__ outW,
    unsigned short* __restrict__ wbf,
    const int* __restrict__ dst, int* __restrict__ bh,
    int E, int chunk, int nblk)
{
    __shared__ char smem[128 * 17 * 2];
    int t = threadIdx.x;
    if (blockIdx.x < 24) {
        unsigned short (*tile)[17] = reinterpret_cast<unsigned short (*)[17]>(smem);
        int blk = blockIdx.x;
        int mat = blk >> 3, s = blk & 7;
        const float* src = (mat < 2) ? (W + (size_t)mat * D * D) : outW;
        unsigned short* dstp = wbf + (size_t)mat * D * D;
        int n0 = s * 16;
#pragma unroll
        for (int it = 0; it < 8; ++it) {
            int idx = it * 256 + t;
            int k = idx >> 4, n = idx & 15;
            tile[k][n] = f2bf(src[k * D + n0 + n]);
        }
        __syncthreads();
#pragma unroll
        for (int it = 0; it < 8; ++it) {
            int idx = it * 256 + t;
            int n = idx >> 7, k = idx & 127;
            dstp[(size_t)(n0 + n) * D + k] = tile[k][n];
        }
    } else {
        int* h = reinterpret_cast<int*>(smem);
        int b = blockIdx.x - 24;
        h[t] = 0;
        __syncthreads();
        int lo = b * chunk, hi = min(E, lo + chunk);
        for (int i = lo + t; i < hi; i += 256) atomicAdd(&h[dst[i] >> 8], 1);
        __syncthreads();
        bh[t * nblk + b] = h[t];
    }
}

// ---------------- K2: bin_scan (standalone, small) -------------------------
__global__ __launch_bounds__(256) void bin_scan(
    int* __restrict__ bh, int* __restrict__ tot, int nblk)
{
    __shared__ int sh[256];
    int bin = blockIdx.x, t = threadIdx.x;
    int v = (t < nblk) ? bh[bin * nblk + t] : 0;
    sh[t] = v;
    __syncthreads();
#pragma unroll
    for (int off = 1; off < 256; off <<= 1) {
        int x = (t >= off) ? sh[t - off] : 0;
        __syncthreads();
        sh[t] += x;
        __syncthreads();
    }
    if (t < nblk) bh[bin * nblk + t] = sh[t] - v;
    if (t == 255) tot[bin] = sh[255];
}

// ---------------- K3: scatter (NBLK blocks) || gemm layer-0 ----------------
__global__ __launch_bounds__(256) void scatter_gemm0(
    const int* __restrict__ dst, const int* __restrict__ src,
    const int* __restrict__ bh, const int* __restrict__ tot,
    int2* __restrict__ bout, int E, int chunk, int nblk,
    const float* __restrict__ x, const unsigned short* __restrict__ wbf,
    void* __restrict__ hbuf, int nrows)
{
    __shared__ int sh[NBIN];
    __shared__ int cur[NBIN];
    int t = threadIdx.x;
    if (blockIdx.x < nblk) {
        int b = blockIdx.x;
        int tv = tot[t];
        sh[t] = tv;
        __syncthreads();
#pragma unroll
        for (int off = 1; off < 256; off <<= 1) {
            int xq = (t >= off) ? sh[t - off] : 0;
            __syncthreads();
            sh[t] += xq;
            __syncthreads();
        }
        cur[t] = (sh[t] - tv) + bh[t * nblk + b];
        __syncthreads();
        int lo = b * chunk, hi = min(E, lo + chunk);
        for (int i = lo + t; i < hi; i += 256) {
            int d = dst[i];
            int p = atomicAdd(&cur[d >> 8], 1);
            bout[p] = make_int2(src[i], d);
        }
    } else {
        gemm_body<0, 1, 0>(blockIdx.x - nblk, x, wbf, nullptr, hbuf, nrows);
    }
}

// ---------------- standalone gemm layer-1 (bf16 in, gelu) ------------------
__global__ __launch_bounds__(256) void gemm_l1(
    const void* __restrict__ Xv, const unsigned short* __restrict__ Wt,
    void* __restrict__ Outv, int nrows)
{
    gemm_body<1, 1, 1>(blockIdx.x, Xv, Wt, nullptr, Outv, nrows);
}

// ---------------- K4: fused fill (count+scan+rowptr+rank) ------------------
__global__ __launch_bounds__(256) void fill_fused(
    const int2* __restrict__ bout, const int* __restrict__ tot,
    int* __restrict__ rowptr, int* __restrict__ slist, int N, int E)
{
    __shared__ int sh[NBIN];
    __shared__ int cnt[NBIN];
    __shared__ int cur[NBIN];
    int b = blockIdx.x, t = threadIdx.x;

    int tv = tot[t];
    sh[t] = tv;
    __syncthreads();
#pragma unroll
    for (int off = 1; off < 256; off <<= 1) {
        int x = (t >= off) ? sh[t - off] : 0;
        __syncthreads();
        sh[t] += x;
        __syncthreads();
    }
    int hi = sh[b];
    int lo = hi - tot[b];

    cnt[t] = 0;
    __syncthreads();
    for (int i = lo + t; i < hi; i += 256) atomicAdd(&cnt[bout[i].y & 255], 1);
    __syncthreads();

    int cv = cnt[t];
    sh[t] = cv;
    __syncthreads();
#pragma unroll
    for (int off = 1; off < 256; off <<= 1) {
        int x = (t >= off) ? sh[t - off] : 0;
        __syncthreads();
        sh[t] += x;
        __syncthreads();
    }
    int start = lo + sh[t] - cv;
    int d0 = b * 256 + t;
    if (d0 < N) rowptr[d0] = start;
    if (b == (int)gridDim.x - 1 && t == 255) rowptr[N] = E;
    cur[t] = start;
    __syncthreads();

    for (int i = lo + t; i < hi; i += 256) {
        int2 e = bout[i];
        int p = atomicAdd(&cur[e.y & 255], 1);
        slist[p] = e.x;
    }
}

// ----------- aggregate: r14 shape + abs-modifier leaky ---------------------
// leaky(v) = 0.6v + 0.4|v| exactly (slope 0.2); |v| is a free VOP3 src mod.
// aw1 = att*0.6*log2e, aw2 = att*0.4*log2e -> logit contribution = 4 FMAs.
#define PROC(u, k) \
    float h##k##x = bf2f((u) & 0xffffu), h##k##y = bf2f((u) >> 16); \
    float v##k##0 = h##k##x + hdx, v##k##1 = h##k##y + hdy; \
    float p##k = fmaf(aw1.x, v##k##0, fmaf(aw2.x, fabsf(v##k##0), \
                 fmaf(aw1.y, v##k##1, aw2.y * fabsf(v##k##1)))); \
    DPP_ADD(p##k, 0xB1); DPP_ADD(p##k, 0x4E); DPP_ADD(p##k, 0x141); \
    float e##k = exp2_hw(p##k);

#define QUAD_BODY(U0, U1, U2, U3) \
    { PROC(U0, 0) PROC(U1, 1) PROC(U2, 2) PROC(U3, 3) \
      ssum += (e0 + e1) + (e2 + e3); \
      accx = fmaf(e0, h0x, fmaf(e1, h1x, fmaf(e2, h2x, fmaf(e3, h3x, accx)))); \
      accy = fmaf(e0, h0y, fmaf(e1, h1y, fmaf(e2, h2y, fmaf(e3, h3y, accy)))); }

__global__ __launch_bounds__(256) void aggregate(
    const unsigned int* __restrict__ Hm,
    const int* __restrict__ rowptr, const int* __restrict__ slist,
    const float* __restrict__ att, const float* __restrict__ bias,
    unsigned int* __restrict__ Outv, int n)
{
    int wid  = threadIdx.x >> 6;
    int lane = threadIdx.x & 63;
    int d = blockIdx.x * 4 + wid;
    if (d >= n) return;

    int beg = __builtin_amdgcn_readfirstlane(rowptr[d]);
    int end = __builtin_amdgcn_readfirstlane(rowptr[d + 1]);

    unsigned int ud = Hm[((unsigned)d << 6) | lane];
    float hdx = bf2f(ud & 0xffffu), hdy = bf2f(ud >> 16);
    float2 aw = reinterpret_cast<const float2*>(att)[lane];
    float2 aw1, aw2;
    aw1.x = aw.x * 0.86561702453f;  // 0.6 * log2(e)
    aw1.y = aw.y * 0.86561702453f;
    aw2.x = aw.x * 0.57707801636f;  // 0.4 * log2(e)
    aw2.y = aw.y * 0.57707801636f;

    float ssum = 0.f, accx = 0.f, accy = 0.f;

    int nfull = (end - beg) >> 2;
    int ii = beg;
    unsigned cu0, cu1, cu2, cu3;
    if (nfull) {
        cu0 = Hm[((unsigned)slist[ii]     << 6) | lane];
        cu1 = Hm[((unsigned)slist[ii + 1] << 6) | lane];
        cu2 = Hm[((unsigned)slist[ii + 2] << 6) | lane];
        cu3 = Hm[((unsigned)slist[ii + 3] << 6) | lane];
    }
    for (int q = 1; q < nfull; ++q) {
        int j = ii + 4;
        unsigned nu0 = Hm[((unsigned)slist[j]     << 6) | lane];
        unsigned nu1 = Hm[((unsigned)slist[j + 1] << 6) | lane];
        unsigned nu2 = Hm[((unsigned)slist[j + 2] << 6) | lane];
        unsigned nu3 = Hm[((unsigned)slist[j + 3] << 6) | lane];
        QUAD_BODY(cu0, cu1, cu2, cu3)
        cu0 = nu0; cu1 = nu1; cu2 = nu2; cu3 = nu3;
        ii = j;
    }
    if (nfull) {
        QUAD_BODY(cu0, cu1, cu2, cu3)
        ii += 4;
    }
    for (; ii < end; ++ii) {
        unsigned u0 = Hm[((unsigned)slist[ii] << 6) | lane];
        PROC(u0, 9)
        ssum += e9;
        accx = fmaf(e9, h9x, accx);
        accy = fmaf(e9, h9y, accy);
    }

    float inv = 1.f / (ssum + 1e-16f);
    float2 bv = reinterpret_cast<const float2*>(bias)[lane];
    float ox = accx * inv + bv.x;
    float oy = accy * inv + bv.y;
    Outv[((unsigned)d << 6) | lane] =
        (unsigned int)f2bf(ox) | ((unsigned int)f2bf(oy) << 16);
}

// ---------------------------------------------------------------------------
extern "C" void kernel_launch(void* const* d_in, const int* in_sizes, int n_in,
                              void* d_out, int out_size, void* d_ws, size_t ws_size,
                              hipStream_t stream)
{
    const float* x    = (const float*)d_in[0];
    const int*   edge = (const int*)d_in[1];     // int32 (harness converts int64)
    const float* W    = (const float*)d_in[2];
    const float* att  = (const float*)d_in[3];
    const float* bias = (const float*)d_in[4];
    const float* outW = (const float*)d_in[5];
    const float* outb = (const float*)d_in[6];
    const float* lng  = (const float*)d_in[7];
    const float* lnb  = (const float*)d_in[8];

    const int N  = in_sizes[0] / D;
    const int E  = in_sizes[1] / 2;
    const int NT = out_size / D;

    const int* srcp = edge;
    const int* dstp = edge + E;

    auto align256 = [](size_t v) { return (v + 255) & ~(size_t)255; };
    auto cdiv = [](int a, int b) { return (a + b - 1) / b; };

    const int CHUNK = cdiv(E, 256);
    const int NBLK  = cdiv(E, CHUNK);        // <= 256
    const int NBKT  = cdiv(N, 256);
    const int NG    = cdiv(N, 64);           // gemm blocks (N rows)

    char* wp = (char*)d_ws;
    size_t off = 0;
    void* hbuf   = (void*)(wp + off); off += align256((size_t)N * D * 2);
    void* xbuf   = (void*)(wp + off); off += align256((size_t)N * D * 2);
    unsigned short* wbf = (unsigned short*)(wp + off); off += align256((size_t)3 * D * D * 2);
    int*  rowptr = (int*)(wp + off);  off += align256((size_t)(N + 1) * 4);
    int*  slist  = (int*)(wp + off);  off += align256((size_t)E * 4);
    int2* bout   = (int2*)(wp + off); off += align256((size_t)E * 8);
    int*  bh     = (int*)(wp + off);  off += align256((size_t)NBIN * NBLK * 4);
    int*  tot    = (int*)(wp + off);  off += align256((size_t)NBIN * 4);
    (void)n_in; (void)ws_size;

    // K1: W transpose (24 blocks) || edge histogram (NBLK blocks)
    prep_kernel<<<24 + NBLK, 256, 0, stream>>>(W, outW, wbf, dstp, bh, E, CHUNK, NBLK);
    // K2: bin_scan (small)
    bin_scan<<<NBIN, 256, 0, stream>>>(bh, tot, NBLK);
    // K3: scatter (NBLK) || gemm layer-0 (NG)
    scatter_gemm0<<<NBLK + NG, 256, 0, stream>>>(dstp, srcp, bh, tot, bout,
                                                 E, CHUNK, NBLK, x, wbf, hbuf, N);
    // K4: fill
    fill_fused<<<NBKT, 256, 0, stream>>>(bout, tot, rowptr, slist, N, E);
    // K5: aggregate layer-0
    aggregate<<<cdiv(N, 4), 256, 0, stream>>>((unsigned int*)hbuf, rowptr, slist,
                                              att, bias, (unsigned int*)xbuf, N);
    // K6: gemm layer-1 (gelu fused on load)
    gemm_l1<<<NG, 256, 0, stream>>>(xbuf, wbf + D * D, hbuf, N);
    // K7: aggregate layer-1
    aggregate<<<cdiv(N, 4), 256, 0, stream>>>((unsigned int*)hbuf, rowptr, slist,
                                              att + H * C, bias + D, (unsigned int*)xbuf, N);
    // K8: head gemm + fused LayerNorm -> d_out
    gemm_head_ln<<<cdiv(NT, 64), 256, 0, stream>>>(xbuf, wbf + 2 * D * D, outb,
                                                   lng, lnb, (float*)d_out, NT);
}

// Round 17
// 150.889 us; speedup vs baseline: 1.1055x; 1.0245x over previous
//
#include <hip/hip_runtime.h>
#include <math.h>

// ---------------------------------------------------------------------------
// GATv2 encoder. r16 = 154.6us. Aggregate judged at gather-BW floor (~205MB
// L2/L3 per dispatch ~ 34us) - frozen. This round: (1) GEMM col-split across
// waves (32 rows x 128 cols per block -> 6 waves/SIMD, B-loads halved);
// (2) bout packed to 32b (src<<8|dst&255, N<65536); (3) int4 edge reads in
// hist/scatter with 4-aligned CHUNK.
// ---------------------------------------------------------------------------

#define D 128
#define H 8
#define C 16
#define NBIN 256

typedef __attribute__((ext_vector_type(8))) short bf16x8v;
typedef __attribute__((ext_vector_type(4))) float f32x4v;

static __device__ __forceinline__ float bf2f(unsigned int u16) {
    union { unsigned int i; float f; } x; x.i = u16 << 16; return x.f;
}
static __device__ __forceinline__ unsigned short f2bf(float f) {
    union { float f; unsigned int i; } x; x.f = f;
    unsigned int r = x.i + 0x7fffu + ((x.i >> 16) & 1u);   // RNE
    return (unsigned short)(r >> 16);
}
static __device__ __forceinline__ float gelu_f(float v) {
    return 0.5f * v * (1.0f + erff(v * 0.70710678118654752f));
}
static __device__ __forceinline__ float exp2_hw(float x) {   // v_exp_f32 = 2^x
    float r;
    asm("v_exp_f32 %0, %1" : "=v"(r) : "v"(x));
    return r;
}
#define DPP_ADD(v, ctrl) \
    (v) += __builtin_bit_cast(float, __builtin_amdgcn_update_dpp( \
        0, __builtin_bit_cast(int, (v)), (ctrl), 0xf, 0xf, true))

// ----------------- GEMM body: 32 rows/block, col-split waves ---------------
// wave wv: rowhalf = wv>>1 (16 rows), colhalf = wv&1 (64 cols).
template<int IN_BF, int OUT_BF, int GELU>
static __device__ __forceinline__ void gemm_body(
    int bid, const void* __restrict__ Xv, const unsigned short* __restrict__ Wt,
    const float* __restrict__ bias, void* __restrict__ Outv, int nrows)
{
    const int t  = threadIdx.x;
    const int l  = t & 63;
    const int wv = t >> 6;
    const int rh = wv >> 1;
    const int chh = wv & 1;
    const int g  = l >> 4;
    const int r  = l & 15;
    const int m0 = bid * 32 + rh * 16;
    const int row = m0 + r;
    const bool rv = row < nrows;
    const uint4* Wt4 = reinterpret_cast<const uint4*>(Wt);

    bf16x8v afrag[4];
#pragma unroll
    for (int kk = 0; kk < 4; ++kk) {
        int kg = kk * 4 + g;
        float v[8];
        if (IN_BF) {
            uint4 q = make_uint4(0, 0, 0, 0);
            if (rv) q = reinterpret_cast<const uint4*>(Xv)[(size_t)row * 16 + kg];
            if (GELU) {
                unsigned int qq[4] = {q.x, q.y, q.z, q.w};
#pragma unroll
                for (int j = 0; j < 4; ++j) {
                    v[2 * j]     = gelu_f(bf2f(qq[j] & 0xffffu));
                    v[2 * j + 1] = gelu_f(bf2f(qq[j] >> 16));
                }
                short pk[8];
#pragma unroll
                for (int j = 0; j < 8; ++j) pk[j] = (short)f2bf(v[j]);
                afrag[kk] = *reinterpret_cast<bf16x8v*>(pk);
            } else {
                afrag[kk] = __builtin_bit_cast(bf16x8v, q);
            }
        } else {
            float4 a = make_float4(0.f, 0.f, 0.f, 0.f), b = a;
            if (rv) {
                a = reinterpret_cast<const float4*>(Xv)[(size_t)row * 32 + kg * 2];
                b = reinterpret_cast<const float4*>(Xv)[(size_t)row * 32 + kg * 2 + 1];
            }
            v[0] = a.x; v[1] = a.y; v[2] = a.z; v[3] = a.w;
            v[4] = b.x; v[5] = b.y; v[6] = b.z; v[7] = b.w;
            if (GELU) {
#pragma unroll
                for (int j = 0; j < 8; ++j) v[j] = gelu_f(v[j]);
            }
            short pk[8];
#pragma unroll
            for (int j = 0; j < 8; ++j) pk[j] = (short)f2bf(v[j]);
            afrag[kk] = *reinterpret_cast<bf16x8v*>(pk);
        }
    }

    f32x4v acc[4];
#pragma unroll
    for (int ct = 0; ct < 4; ++ct) acc[ct] = (f32x4v){0.f, 0.f, 0.f, 0.f};

    bf16x8v bA[4], bB[4];
#pragma unroll
    for (int ct = 0; ct < 4; ++ct)
        bA[ct] = __builtin_bit_cast(bf16x8v, Wt4[((chh * 4 + ct) * 16 + r) * 16 + g]);

#pragma unroll
    for (int kk = 0; kk < 4; ++kk) {
        if (kk < 3) {
            int kgn = (kk + 1) * 4 + g;
#pragma unroll
            for (int ct = 0; ct < 4; ++ct) {
                bf16x8v v = __builtin_bit_cast(bf16x8v,
                    Wt4[((chh * 4 + ct) * 16 + r) * 16 + kgn]);
                if (kk & 1) bA[ct] = v; else bB[ct] = v;
            }
        }
#pragma unroll
        for (int ct = 0; ct < 4; ++ct) {
            bf16x8v b = (kk & 1) ? bB[ct] : bA[ct];
            acc[ct] = __builtin_amdgcn_mfma_f32_16x16x32_bf16(afrag[kk], b, acc[ct], 0, 0, 0);
        }
    }

#pragma unroll
    for (int ct = 0; ct < 4; ++ct) {
        int col = (chh * 4 + ct) * 16 + r;
        float bj = bias ? bias[col] : 0.f;
#pragma unroll
        for (int i = 0; i < 4; ++i) {
            int rr = m0 + g * 4 + i;
            if (rr < nrows) {
                float val = acc[ct][i] + bj;
                if (OUT_BF)
                    reinterpret_cast<unsigned short*>(Outv)[(size_t)rr * 128 + col] = f2bf(val);
                else
                    reinterpret_cast<float*>(Outv)[(size_t)rr * 128 + col] = val;
            }
        }
    }
}

// --------------- head GEMM with fused LayerNorm epilogue -------------------
__global__ __launch_bounds__(256) void gemm_head_ln(
    const void* __restrict__ Xv, const unsigned short* __restrict__ Wt,
    const float* __restrict__ outb, const float* __restrict__ lng,
    const float* __restrict__ lnb, float* __restrict__ Out, int nrows)
{
    const int t  = threadIdx.x;
    const int l  = t & 63;
    const int wv = t >> 6;
    const int g  = l >> 4;
    const int r  = l & 15;
    const int m0 = blockIdx.x * 64;
    const int row = m0 + wv * 16 + r;
    const bool rv = row < nrows;
    const uint4* Wt4 = reinterpret_cast<const uint4*>(Wt);

    bf16x8v afrag[4];
#pragma unroll
    for (int kk = 0; kk < 4; ++kk) {
        int kg = kk * 4 + g;
        uint4 q = make_uint4(0, 0, 0, 0);
        if (rv) q = reinterpret_cast<const uint4*>(Xv)[(size_t)row * 16 + kg];
        afrag[kk] = __builtin_bit_cast(bf16x8v, q);
    }

    f32x4v acc[8];
#pragma unroll
    for (int ct = 0; ct < 8; ++ct) acc[ct] = (f32x4v){0.f, 0.f, 0.f, 0.f};

#pragma unroll
    for (int kk = 0; kk < 4; ++kk) {
        int kg = kk * 4 + g;
#pragma unroll
        for (int ct = 0; ct < 8; ++ct) {
            bf16x8v b = __builtin_bit_cast(bf16x8v, Wt4[(ct * 16 + r) * 16 + kg]);
            acc[ct] = __builtin_amdgcn_mfma_f32_16x16x32_bf16(afrag[kk], b, acc[ct], 0, 0, 0);
        }
    }

    float gmm[8], bbb[8];
#pragma unroll
    for (int ct = 0; ct < 8; ++ct) {
        gmm[ct] = lng[ct * 16 + r];
        bbb[ct] = lnb[ct * 16 + r];
    }

#pragma unroll
    for (int i = 0; i < 4; ++i) {
        int rr = m0 + wv * 16 + g * 4 + i;
        if (rr >= nrows) continue;   // uniform within the 16-lane row group
        float v[8];
        float s = 0.f;
#pragma unroll
        for (int ct = 0; ct < 8; ++ct) {
            v[ct] = acc[ct][i] + outb[ct * 16 + r];
            s += v[ct];
        }
        DPP_ADD(s, 0xB1); DPP_ADD(s, 0x4E); DPP_ADD(s, 0x141); DPP_ADD(s, 0x140);
        float mu = s * (1.f / 128.f);
        float q = 0.f;
#pragma unroll
        for (int ct = 0; ct < 8; ++ct) {
            float dd = v[ct] - mu;
            q += dd * dd;
        }
        DPP_ADD(q, 0xB1); DPP_ADD(q, 0x4E); DPP_ADD(q, 0x141); DPP_ADD(q, 0x140);
        float inv = rsqrtf(q * (1.f / 128.f) + 1e-12f);
#pragma unroll
        for (int ct = 0; ct < 8; ++ct)
            Out[(size_t)rr * 128 + ct * 16 + r] = (v[ct] - mu) * inv * gmm[ct] + bbb[ct];
    }
}

// ---------------- K1: W transpose (24 blocks) || edge histogram ------------
__global__ __launch_bounds__(256) void prep_kernel(
    const float* __restrict__ W, const float* __restrict__ outW,
    unsigned short* __restrict__ wbf,
    const int* __restrict__ dst, int* __restrict__ bh,
    int E, int chunk, int nblk)
{
    __shared__ char smem[128 * 17 * 2];
    int t = threadIdx.x;
    if (blockIdx.x < 24) {
        unsigned short (*tile)[17] = reinterpret_cast<unsigned short (*)[17]>(smem);
        int blk = blockIdx.x;
        int mat = blk >> 3, s = blk & 7;
        const float* src = (mat < 2) ? (W + (size_t)mat * D * D) : outW;
        unsigned short* dstp = wbf + (size_t)mat * D * D;
        int n0 = s * 16;
#pragma unroll
        for (int it = 0; it < 8; ++it) {
            int idx = it * 256 + t;
            int k = idx >> 4, n = idx & 15;
            tile[k][n] = f2bf(src[k * D + n0 + n]);
        }
        __syncthreads();
#pragma unroll
        for (int it = 0; it < 8; ++it) {
            int idx = it * 256 + t;
            int n = idx >> 7, k = idx & 127;
            dstp[(size_t)(n0 + n) * D + k] = tile[k][n];
        }
    } else {
        int* h = reinterpret_cast<int*>(smem);
        int b = blockIdx.x - 24;
        h[t] = 0;
        __syncthreads();
        int lo = b * chunk, hi = min(E, lo + chunk);
        // chunk is 4-aligned and lo is 16B-aligned: int4 main loop
        int i = lo + t * 4;
        for (; i + 3 < hi; i += 1024) {
            int4 q = *reinterpret_cast<const int4*>(dst + i);
            atomicAdd(&h[q.x >> 8], 1);
            atomicAdd(&h[q.y >> 8], 1);
            atomicAdd(&h[q.z >> 8], 1);
            atomicAdd(&h[q.w >> 8], 1);
        }
        for (; i < hi; ++i) atomicAdd(&h[dst[i] >> 8], 1);
        __syncthreads();
        bh[t * nblk + b] = h[t];
    }
}

// ---------------- K2: bin_scan (standalone, small) -------------------------
__global__ __launch_bounds__(256) void bin_scan(
    int* __restrict__ bh, int* __restrict__ tot, int nblk)
{
    __shared__ int sh[256];
    int bin = blockIdx.x, t = threadIdx.x;
    int v = (t < nblk) ? bh[bin * nblk + t] : 0;
    sh[t] = v;
    __syncthreads();
#pragma unroll
    for (int off = 1; off < 256; off <<= 1) {
        int x = (t >= off) ? sh[t - off] : 0;
        __syncthreads();
        sh[t] += x;
        __syncthreads();
    }
    if (t < nblk) bh[bin * nblk + t] = sh[t] - v;
    if (t == 255) tot[bin] = sh[255];
}

// ---------------- K3: scatter (NBLK blocks) || gemm layer-0 ----------------
// bout packed: (src<<8) | (dst&255)  [valid: N < 65536]
__global__ __launch_bounds__(256) void scatter_gemm0(
    const int* __restrict__ dst, const int* __restrict__ src,
    const int* __restrict__ bh, const int* __restrict__ tot,
    unsigned int* __restrict__ bout, int E, int chunk, int nblk,
    const float* __restrict__ x, const unsigned short* __restrict__ wbf,
    void* __restrict__ hbuf, int nrows)
{
    __shared__ int sh[NBIN];
    __shared__ int cur[NBIN];
    int t = threadIdx.x;
    if (blockIdx.x < nblk) {
        int b = blockIdx.x;
        int tv = tot[t];
        sh[t] = tv;
        __syncthreads();
#pragma unroll
        for (int off = 1; off < 256; off <<= 1) {
            int xq = (t >= off) ? sh[t - off] : 0;
            __syncthreads();
            sh[t] += xq;
            __syncthreads();
        }
        cur[t] = (sh[t] - tv) + bh[t * nblk + b];
        __syncthreads();
        int lo = b * chunk, hi = min(E, lo + chunk);
        int i = lo + t * 4;
        for (; i + 3 < hi; i += 1024) {
            int4 dq = *reinterpret_cast<const int4*>(dst + i);
            int4 sq = *reinterpret_cast<const int4*>(src + i);
            int p0 = atomicAdd(&cur[dq.x >> 8], 1);
            bout[p0] = ((unsigned)sq.x << 8) | (dq.x & 255);
            int p1 = atomicAdd(&cur[dq.y >> 8], 1);
            bout[p1] = ((unsigned)sq.y << 8) | (dq.y & 255);
            int p2 = atomicAdd(&cur[dq.z >> 8], 1);
            bout[p2] = ((unsigned)sq.z << 8) | (dq.z & 255);
            int p3 = atomicAdd(&cur[dq.w >> 8], 1);
            bout[p3] = ((unsigned)sq.w << 8) | (dq.w & 255);
        }
        for (; i < hi; ++i) {
            int d = dst[i];
            int p = atomicAdd(&cur[d >> 8], 1);
            bout[p] = ((unsigned)src[i] << 8) | (d & 255);
        }
    } else {
        gemm_body<0, 1, 0>(blockIdx.x - nblk, x, wbf, nullptr, hbuf, nrows);
    }
}

// ---------------- standalone gemm layer-1 (bf16 in, gelu) ------------------
__global__ __launch_bounds__(256) void gemm_l1(
    const void* __restrict__ Xv, const unsigned short* __restrict__ Wt,
    void* __restrict__ Outv, int nrows)
{
    gemm_body<1, 1, 1>(blockIdx.x, Xv, Wt, nullptr, Outv, nrows);
}

// ---------------- K4: fused fill (count+scan+rowptr+rank) ------------------
__global__ __launch_bounds__(256) void fill_fused(
    const unsigned int* __restrict__ bout, const int* __restrict__ tot,
    int* __restrict__ rowptr, int* __restrict__ slist, int N, int E)
{
    __shared__ int sh[NBIN];
    __shared__ int cnt[NBIN];
    __shared__ int cur[NBIN];
    int b = blockIdx.x, t = threadIdx.x;

    int tv = tot[t];
    sh[t] = tv;
    __syncthreads();
#pragma unroll
    for (int off = 1; off < 256; off <<= 1) {
        int x = (t >= off) ? sh[t - off] : 0;
        __syncthreads();
        sh[t] += x;
        __syncthreads();
    }
    int hi = sh[b];
    int lo = hi - tot[b];

    cnt[t] = 0;
    __syncthreads();
    for (int i = lo + t; i < hi; i += 256) atomicAdd(&cnt[bout[i] & 255], 1);
    __syncthreads();

    int cv = cnt[t];
    sh[t] = cv;
    __syncthreads();
#pragma unroll
    for (int off = 1; off < 256; off <<= 1) {
        int x = (t >= off) ? sh[t - off] : 0;
        __syncthreads();
        sh[t] += x;
        __syncthreads();
    }
    int start = lo + sh[t] - cv;
    int d0 = b * 256 + t;
    if (d0 < N) rowptr[d0] = start;
    if (b == (int)gridDim.x - 1 && t == 255) rowptr[N] = E;
    cur[t] = start;
    __syncthreads();

    for (int i = lo + t; i < hi; i += 256) {
        unsigned e = bout[i];
        int p = atomicAdd(&cur[e & 255], 1);
        slist[p] = (int)(e >> 8);
    }
}

// ----------- aggregate: abs-modifier leaky, 4-deep quads -------------------
#define PROC(u, k) \
    float h##k##x = bf2f((u) & 0xffffu), h##k##y = bf2f((u) >> 16); \
    float v##k##0 = h##k##x + hdx, v##k##1 = h##k##y + hdy; \
    float p##k = fmaf(aw1.x, v##k##0, fmaf(aw2.x, fabsf(v##k##0), \
                 fmaf(aw1.y, v##k##1, aw2.y * fabsf(v##k##1)))); \
    DPP_ADD(p##k, 0xB1); DPP_ADD(p##k, 0x4E); DPP_ADD(p##k, 0x141); \
    float e##k = exp2_hw(p##k);

#define QUAD_BODY(U0, U1, U2, U3) \
    { PROC(U0, 0) PROC(U1, 1) PROC(U2, 2) PROC(U3, 3) \
      ssum += (e0 + e1) + (e2 + e3); \
      accx = fmaf(e0, h0x, fmaf(e1, h1x, fmaf(e2, h2x, fmaf(e3, h3x, accx)))); \
      accy = fmaf(e0, h0y, fmaf(e1, h1y, fmaf(e2, h2y, fmaf(e3, h3y, accy)))); }

__global__ __launch_bounds__(256) void aggregate(
    const unsigned int* __restrict__ Hm,
    const int* __restrict__ rowptr, const int* __restrict__ slist,
    const float* __restrict__ att, const float* __restrict__ bias,
    unsigned int* __restrict__ Outv, int n)
{
    int wid  = threadIdx.x >> 6;
    int lane = threadIdx.x & 63;
    int d = blockIdx.x * 4 + wid;
    if (d >= n) return;

    int beg = __builtin_amdgcn_readfirstlane(rowptr[d]);
    int end = __builtin_amdgcn_readfirstlane(rowptr[d + 1]);

    unsigned int ud = Hm[((unsigned)d << 6) | lane];
    float hdx = bf2f(ud & 0xffffu), hdy = bf2f(ud >> 16);
    float2 aw = reinterpret_cast<const float2*>(att)[lane];
    float2 aw1, aw2;
    aw1.x = aw.x * 0.86561702453f;  // 0.6 * log2(e)
    aw1.y = aw.y * 0.86561702453f;
    aw2.x = aw.x * 0.57707801636f;  // 0.4 * log2(e)
    aw2.y = aw.y * 0.57707801636f;

    float ssum = 0.f, accx = 0.f, accy = 0.f;

    int nfull = (end - beg) >> 2;
    int ii = beg;
    unsigned cu0, cu1, cu2, cu3;
    if (nfull) {
        cu0 = Hm[((unsigned)slist[ii]     << 6) | lane];
        cu1 = Hm[((unsigned)slist[ii + 1] << 6) | lane];
        cu2 = Hm[((unsigned)slist[ii + 2] << 6) | lane];
        cu3 = Hm[((unsigned)slist[ii + 3] << 6) | lane];
    }
    for (int q = 1; q < nfull; ++q) {
        int j = ii + 4;
        unsigned nu0 = Hm[((unsigned)slist[j]     << 6) | lane];
        unsigned nu1 = Hm[((unsigned)slist[j + 1] << 6) | lane];
        unsigned nu2 = Hm[((unsigned)slist[j + 2] << 6) | lane];
        unsigned nu3 = Hm[((unsigned)slist[j + 3] << 6) | lane];
        QUAD_BODY(cu0, cu1, cu2, cu3)
        cu0 = nu0; cu1 = nu1; cu2 = nu2; cu3 = nu3;
        ii = j;
    }
    if (nfull) {
        QUAD_BODY(cu0, cu1, cu2, cu3)
        ii += 4;
    }
    for (; ii < end; ++ii) {
        unsigned u0 = Hm[((unsigned)slist[ii] << 6) | lane];
        PROC(u0, 9)
        ssum += e9;
        accx = fmaf(e9, h9x, accx);
        accy = fmaf(e9, h9y, accy);
    }

    float inv = 1.f / (ssum + 1e-16f);
    float2 bv = reinterpret_cast<const float2*>(bias)[lane];
    float ox = accx * inv + bv.x;
    float oy = accy * inv + bv.y;
    Outv[((unsigned)d << 6) | lane] =
        (unsigned int)f2bf(ox) | ((unsigned int)f2bf(oy) << 16);
}

// ---------------------------------------------------------------------------
extern "C" void kernel_launch(void* const* d_in, const int* in_sizes, int n_in,
                              void* d_out, int out_size, void* d_ws, size_t ws_size,
                              hipStream_t stream)
{
    const float* x    = (const float*)d_in[0];
    const int*   edge = (const int*)d_in[1];     // int32 (harness converts int64)
    const float* W    = (const float*)d_in[2];
    const float* att  = (const float*)d_in[3];
    const float* bias = (const float*)d_in[4];
    const float* outW = (const float*)d_in[5];
    const float* outb = (const float*)d_in[6];
    const float* lng  = (const float*)d_in[7];
    const float* lnb  = (const float*)d_in[8];

    const int N  = in_sizes[0] / D;
    const int E  = in_sizes[1] / 2;
    const int NT = out_size / D;

    const int* srcp = edge;
    const int* dstp = edge + E;

    auto align256 = [](size_t v) { return (v + 255) & ~(size_t)255; };
    auto cdiv = [](int a, int b) { return (a + b - 1) / b; };

    const int CHUNK = (cdiv(E, 256) + 3) & ~3;   // 4-aligned for int4 loads
    const int NBLK  = cdiv(E, CHUNK);            // <= 256
    const int NBKT  = cdiv(N, 256);
    const int NG    = cdiv(N, 32);               // gemm blocks (32 rows each)

    char* wp = (char*)d_ws;
    size_t off = 0;
    void* hbuf   = (void*)(wp + off); off += align256((size_t)N * D * 2);
    void* xbuf   = (void*)(wp + off); off += align256((size_t)N * D * 2);
    unsigned short* wbf = (unsigned short*)(wp + off); off += align256((size_t)3 * D * D * 2);
    int*  rowptr = (int*)(wp + off);  off += align256((size_t)(N + 1) * 4);
    int*  slist  = (int*)(wp + off);  off += align256((size_t)E * 4);
    unsigned int* bout = (unsigned int*)(wp + off); off += align256((size_t)E * 4);
    int*  bh     = (int*)(wp + off);  off += align256((size_t)NBIN * NBLK * 4);
    int*  tot    = (int*)(wp + off);  off += align256((size_t)NBIN * 4);
    (void)n_in; (void)ws_size;

    // K1: W transpose (24 blocks) || edge histogram (NBLK blocks)
    prep_kernel<<<24 + NBLK, 256, 0, stream>>>(W, outW, wbf, dstp, bh, E, CHUNK, NBLK);
    // K2: bin_scan (small)
    bin_scan<<<NBIN, 256, 0, stream>>>(bh, tot, NBLK);
    // K3: scatter (NBLK) || gemm layer-0 (NG)
    scatter_gemm0<<<NBLK + NG, 256, 0, stream>>>(dstp, srcp, bh, tot, bout,
                                                 E, CHUNK, NBLK, x, wbf, hbuf, N);
    // K4: fill
    fill_fused<<<NBKT, 256, 0, stream>>>(bout, tot, rowptr, slist, N, E);
    // K5: aggregate layer-0
    aggregate<<<cdiv(N, 4), 256, 0, stream>>>((unsigned int*)hbuf, rowptr, slist,
                                              att, bias, (unsigned int*)xbuf, N);
    // K6: gemm layer-1 (gelu fused on load)
    gemm_l1<<<NG, 256, 0, stream>>>(xbuf, wbf + D * D, hbuf, N);
    // K7: aggregate layer-1
    aggregate<<<cdiv(N, 4), 256, 0, stream>>>((unsigned int*)hbuf, rowptr, slist,
                                              att + H * C, bias + D, (unsigned int*)xbuf, N);
    // K8: head gemm + fused LayerNorm -> d_out
    gemm_head_ln<<<cdiv(NT, 64), 256, 0, stream>>>(xbuf, wbf + 2 * D * D, outb,
                                                   lng, lnb, (float*)d_out, NT);
}